// Round 1
// baseline (132.473 us; speedup 1.0000x reference)
//
#include <hip/hip_runtime.h>

// Double-sparse matvec: y = A @ (B @ x), ELL form.
// M=N=K=8192, NNZ=256 per row, BATCH=32, fp32.
// Stage 1: bx[k][b] = sum_j b_vals[k][j] * x[b_idx[k][j]][b]   -> d_ws (1 MB)
// Stage 2: out[b*M+m] = sum_j a_vals[m][j] * bx[a_idx[m][j]][b]

#define DIM_M 8192
#define NNZ   256
#define BATCH 32

// One wave (64 lanes) per sparse row. lane = h*32 + b:
//   b = batch column (gathers are 32x4B contiguous = coalesced 128B)
//   h = which half of each pair of float4/int4 nnz groups this lane handles.
template <bool TRANSPOSED_OUT>
__global__ __launch_bounds__(256) void ell_spmv(
    const int*   __restrict__ idx,   // [rows, NNZ]
    const float* __restrict__ vals,  // [rows, NNZ]
    const float* __restrict__ src,   // [src_rows, BATCH]
    float*       __restrict__ dst,   // [rows, BATCH] or [BATCH, rows]
    int rows)
{
    const int wave = threadIdx.x >> 6;          // 0..3
    const int lane = threadIdx.x & 63;
    const int r    = blockIdx.x * 4 + wave;     // sparse row
    const int b    = lane & 31;                 // batch column
    const int h    = lane >> 5;                 // 0 or 1

    const float4* v4 = (const float4*)(vals + (size_t)r * NNZ);
    const int4*   i4 = (const int4*)(idx  + (size_t)r * NNZ);

    float acc = 0.f;
    // 64 float4-groups per row; each iteration consumes 2 groups (one per half).
    #pragma unroll 4
    for (int g = 0; g < NNZ / 4; g += 2) {
        const float4 v = v4[g + h];
        const int4   i = i4[g + h];
        acc += v.x * src[(size_t)i.x * BATCH + b];
        acc += v.y * src[(size_t)i.y * BATCH + b];
        acc += v.z * src[(size_t)i.z * BATCH + b];
        acc += v.w * src[(size_t)i.w * BATCH + b];
    }
    // combine the two halves (lane ^ 32)
    acc += __shfl_xor(acc, 32);

    if (h == 0) {
        if (TRANSPOSED_OUT)
            dst[(size_t)b * rows + r] = acc;    // out[b*M + m]
        else
            dst[(size_t)r * BATCH + b] = acc;   // bx[k*BATCH + b]
    }
}

extern "C" void kernel_launch(void* const* d_in, const int* in_sizes, int n_in,
                              void* d_out, int out_size, void* d_ws, size_t ws_size,
                              hipStream_t stream) {
    // setup_inputs order: x, a_idx, a_vals, b_idx, b_vals
    const float* x      = (const float*)d_in[0];   // [N, BATCH]
    const int*   a_idx  = (const int*)  d_in[1];   // [M, NNZ]
    const float* a_vals = (const float*)d_in[2];   // [M, NNZ]
    const int*   b_idx  = (const int*)  d_in[3];   // [K, NNZ]
    const float* b_vals = (const float*)d_in[4];   // [K, NNZ]
    float*       out    = (float*)d_out;           // [BATCH, M]
    float*       bx     = (float*)d_ws;            // [K, BATCH] = 1 MB scratch

    const int rows = DIM_M;                        // M == K == 8192
    dim3 block(256);
    dim3 grid(rows / 4);

    ell_spmv<false><<<grid, block, 0, stream>>>(b_idx, b_vals, x,  bx,  rows);
    ell_spmv<true ><<<grid, block, 0, stream>>>(a_idx, a_vals, bx, out, rows);
}

// Round 2
// 122.273 us; speedup vs baseline: 1.0834x; 1.0834x over previous
//
#include <hip/hip_runtime.h>

// Double-sparse matvec: y = A @ (B @ x), ELL form.
// M=N=K=8192, NNZ=256 per row, BATCH=32, fp32.
// Stage 1: bx[k][b] = sum_j b_vals[k][j] * x[b_idx[k][j]][b]   -> d_ws (1 MB)
// Stage 2: out[b*M+m] = sum_j a_vals[m][j] * bx[a_idx[m][j]][b]
//
// Lane layout (the R1 fix): lane = q*8 + s.
//   s in [0,8): batch quad — this lane covers batch columns [4s, 4s+4) via float4
//   q in [0,8): index slot — 8 sparse indices are serviced per gather instruction
// One global_load_dwordx4 per lane => wave reads 8 distinct 128B x-rows = 1 KiB
// per VMEM instruction (vs 256B for the scalar-gather version). 32 gathers/row
// instead of 128 => 4x less VMEM issue / L1 lookup pressure.

#define NNZ    256
#define BATCH  32
#define ROWS   8192

template <bool TRANSPOSED_OUT>
__global__ __launch_bounds__(256) void ell_spmv4(
    const int*   __restrict__ idx,   // [ROWS, NNZ]
    const float* __restrict__ vals,  // [ROWS, NNZ]
    const float* __restrict__ src,   // [src_rows, BATCH]
    float*       __restrict__ dst)   // [ROWS, BATCH] or [BATCH, ROWS]
{
    __shared__ float tile[4][BATCH];            // only used when TRANSPOSED_OUT

    const int wave = threadIdx.x >> 6;          // 0..3
    const int lane = threadIdx.x & 63;
    const int r    = blockIdx.x * 4 + wave;     // sparse row
    const int s    = lane & 7;                  // batch quad id
    const int q    = lane >> 3;                 // index slot in group of 8

    const int rowoff = r * NNZ;
    float4 acc = {0.f, 0.f, 0.f, 0.f};

    #pragma unroll 4
    for (int g = 0; g < NNZ / 8; ++g) {
        const int   j  = rowoff + g * 8 + q;
        const int   ix = __builtin_nontemporal_load(idx + j);   // stream, don't pollute L2
        const float v  = __builtin_nontemporal_load(vals + j);
        const float4 xv = *(const float4*)(src + ix * BATCH + s * 4);  // 32-bit addr math
        acc.x += v * xv.x;
        acc.y += v * xv.y;
        acc.z += v * xv.z;
        acc.w += v * xv.w;
    }

    // reduce across the 8 index slots (lanes strided by 8): xor 8, 16, 32
    #pragma unroll
    for (int d = 8; d < 64; d <<= 1) {
        acc.x += __shfl_xor(acc.x, d);
        acc.y += __shfl_xor(acc.y, d);
        acc.z += __shfl_xor(acc.z, d);
        acc.w += __shfl_xor(acc.w, d);
    }

    if (!TRANSPOSED_OUT) {
        if (q == 0)                                       // lanes 0..7: 128B coalesced store
            *(float4*)(dst + r * BATCH + s * 4) = acc;
    } else {
        if (q == 0)
            *(float4*)(&tile[wave][s * 4]) = acc;
        __syncthreads();
        // out[b*ROWS + r0 + rr]: 16B-contiguous segments per batch row
        const int t = threadIdx.x;
        if (t < 4 * BATCH) {
            const int b  = t >> 2;
            const int rr = t & 3;
            dst[b * ROWS + blockIdx.x * 4 + rr] = tile[rr][b];
        }
    }
}

extern "C" void kernel_launch(void* const* d_in, const int* in_sizes, int n_in,
                              void* d_out, int out_size, void* d_ws, size_t ws_size,
                              hipStream_t stream) {
    // setup_inputs order: x, a_idx, a_vals, b_idx, b_vals
    const float* x      = (const float*)d_in[0];   // [N, BATCH]
    const int*   a_idx  = (const int*)  d_in[1];   // [M, NNZ]
    const float* a_vals = (const float*)d_in[2];   // [M, NNZ]
    const int*   b_idx  = (const int*)  d_in[3];   // [K, NNZ]
    const float* b_vals = (const float*)d_in[4];   // [K, NNZ]
    float*       out    = (float*)d_out;           // [BATCH, M]
    float*       bx     = (float*)d_ws;            // [K, BATCH] = 1 MB scratch

    dim3 block(256);
    dim3 grid(ROWS / 4);

    ell_spmv4<false><<<grid, block, 0, stream>>>(b_idx, b_vals, x,  bx);
    ell_spmv4<true ><<<grid, block, 0, stream>>>(a_idx, a_vals, bx, out);
}

// Round 4
// 120.467 us; speedup vs baseline: 1.0997x; 1.0150x over previous
//
#include <hip/hip_runtime.h>

// Double-sparse matvec: y = A @ (B @ x), ELL form.
// M=N=K=8192, NNZ=256 per row, BATCH=32, fp32.
// Stage 1: bx[k][b] = sum_j b_vals[k][j] * x[b_idx[k][j]][b]   -> d_ws (1 MB)
// Stage 2: out[b*M+m] = sum_j a_vals[m][j] * bx[a_idx[m][j]][b]
//
// Lane layout: lane = q*8 + s.
//   s in [0,8): batch quad — lane covers batch columns [4s, 4s+4) via float4
//   q in [0,8): owns the CONSECUTIVE index block j = q*32 .. q*32+31
// Consecutive ownership lets each lane load its idx/vals as 16B vectors:
//   8 idx + 8 vals loads per row (128B utilized per wave per instruction)
// instead of 64 scalar-dword loads (32B utilized). Gathers: 32 per row,
// each instruction = 8 distinct 128B src-rows (1 KiB utilized).

#define NNZ    256
#define BATCH  32
#define ROWS   8192

// Native clang vectors: required by __builtin_nontemporal_load (HIP_vector_type
// structs are rejected), and same 16B codegen.
typedef int   vi4 __attribute__((ext_vector_type(4)));
typedef float vf4 __attribute__((ext_vector_type(4)));

template <bool TRANSPOSED_OUT>
__global__ __launch_bounds__(256) void ell_spmv4(
    const int*   __restrict__ idx,   // [ROWS, NNZ]
    const float* __restrict__ vals,  // [ROWS, NNZ]
    const float* __restrict__ src,   // [src_rows, BATCH]
    float*       __restrict__ dst)   // [ROWS, BATCH] or [BATCH, ROWS]
{
    __shared__ float tile[4][BATCH];            // only used when TRANSPOSED_OUT

    const int wave = threadIdx.x >> 6;          // 0..3
    const int lane = threadIdx.x & 63;
    const int r    = blockIdx.x * 4 + wave;     // sparse row
    const int s    = lane & 7;                  // batch quad id
    const int q    = lane >> 3;                 // consecutive index block of 32

    const vi4* i4 = (const vi4*)(idx  + r * NNZ) + q * 8;
    const vf4* v4 = (const vf4*)(vals + r * NNZ) + q * 8;
    const int  soff = s * 4;

    vf4 acc = {0.f, 0.f, 0.f, 0.f};

    #pragma unroll
    for (int t = 0; t < 8; ++t) {
        const vi4 iv = __builtin_nontemporal_load(i4 + t);   // stream once
        const vf4 vv = __builtin_nontemporal_load(v4 + t);
        {
            const vf4 xv = *(const vf4*)(src + iv.x * BATCH + soff);
            acc += vv.x * xv;
        }
        {
            const vf4 xv = *(const vf4*)(src + iv.y * BATCH + soff);
            acc += vv.y * xv;
        }
        {
            const vf4 xv = *(const vf4*)(src + iv.z * BATCH + soff);
            acc += vv.z * xv;
        }
        {
            const vf4 xv = *(const vf4*)(src + iv.w * BATCH + soff);
            acc += vv.w * xv;
        }
    }

    // reduce across the 8 q-blocks (lanes strided by 8): xor 8, 16, 32
    #pragma unroll
    for (int d = 8; d < 64; d <<= 1) {
        acc.x += __shfl_xor(acc.x, d);
        acc.y += __shfl_xor(acc.y, d);
        acc.z += __shfl_xor(acc.z, d);
        acc.w += __shfl_xor(acc.w, d);
    }

    if (!TRANSPOSED_OUT) {
        if (q == 0)                                       // lanes 0..7: 128B coalesced store
            *(vf4*)(dst + r * BATCH + soff) = acc;
    } else {
        if (q == 0)
            *(vf4*)(&tile[wave][soff]) = acc;
        __syncthreads();
        // out[b*ROWS + r0 + rr]: 16B-contiguous segments per batch row
        const int t = threadIdx.x;
        if (t < 4 * BATCH) {
            const int b  = t >> 2;
            const int rr = t & 3;
            __builtin_nontemporal_store(tile[rr][b],
                                        dst + b * ROWS + blockIdx.x * 4 + rr);
        }
    }
}

extern "C" void kernel_launch(void* const* d_in, const int* in_sizes, int n_in,
                              void* d_out, int out_size, void* d_ws, size_t ws_size,
                              hipStream_t stream) {
    // setup_inputs order: x, a_idx, a_vals, b_idx, b_vals
    const float* x      = (const float*)d_in[0];   // [N, BATCH]
    const int*   a_idx  = (const int*)  d_in[1];   // [M, NNZ]
    const float* a_vals = (const float*)d_in[2];   // [M, NNZ]
    const int*   b_idx  = (const int*)  d_in[3];   // [K, NNZ]
    const float* b_vals = (const float*)d_in[4];   // [K, NNZ]
    float*       out    = (float*)d_out;           // [BATCH, M]
    float*       bx     = (float*)d_ws;            // [K, BATCH] = 1 MB scratch

    dim3 block(256);
    dim3 grid(ROWS / 4);

    ell_spmv4<false><<<grid, block, 0, stream>>>(b_idx, b_vals, x,  bx);
    ell_spmv4<true ><<<grid, block, 0, stream>>>(a_idx, a_vals, bx, out);
}